// Round 13
// baseline (354.723 us; speedup 1.0000x reference)
//
#include <hip/hip_runtime.h>
#include <math.h>

#define B_ 4
#define L_ 1024
#define DM_ 1024
#define DI_ 2048
#define N_ 16
#define R_ 64
#define BT_ (B_*L_)   // 4096 tokens
#define NX_ 96        // R + 2N
#define CH_ 16        // scan chunks
#define LC_ (L_/CH_)  // 64 steps per chunk
#define KC_ 8         // xdbl k-chunks
#define KCL_ (DI_/KC_)// 256 k per chunk
#define LOG2E_ 1.44269504088896f

typedef unsigned short u16;
typedef unsigned int u32;
typedef short bf16x8 __attribute__((ext_vector_type(8)));
typedef u16 u16x8 __attribute__((ext_vector_type(8)));
typedef float f32x4 __attribute__((ext_vector_type(4)));

__device__ __forceinline__ float silu_f(float x) { return x / (1.f + expf(-x)); }
__device__ __forceinline__ float softplus_f(float x) {
  return x > 0.f ? x + log1pf(expf(-x)) : log1pf(expf(x));
}
__device__ __forceinline__ u16 bf16_rne(float f) {
  u32 u = __float_as_uint(f);
  u32 r = (u + 0x7FFFu + ((u >> 16) & 1u)) >> 16;
  return (u16)r;
}
__device__ __forceinline__ float bf16_to_f(u16 h) {
  return __uint_as_float(((u32)h) << 16);
}
__device__ __forceinline__ void gload_lds16(const void* g, void* l) {
  __builtin_amdgcn_global_load_lds((const __attribute__((address_space(1))) void*)g,
                                   (__attribute__((address_space(3))) void*)l, 16, 0, 0);
}

// swizzled byte offset within a [rows][32] u16 tile (64B rows, 16B granules)
#define SWZ16(r, s) ((r) * 64 + ((((s) ^ (((r) >> 1) & 3))) << 4))

// ---------------- K0a: W_in (1024x4096 f32) -> Wt_hi/Wt_lo (4096x1024 bf16), transposed split
__global__ __launch_bounds__(256) void wsplit_kernel(const float* __restrict__ W,
                                                     u16* __restrict__ Th,
                                                     u16* __restrict__ Tl) {
  __shared__ float tile[32][33];
  const int n0 = blockIdx.x * 32;
  const int k0 = blockIdx.y * 32;
  const int t = threadIdx.x;
  {
    int kr = t >> 3, nc = (t & 7) * 4;
    float4 v = *(const float4*)&W[(size_t)(k0 + kr) * (2 * DI_) + n0 + nc];
    tile[kr][nc + 0] = v.x; tile[kr][nc + 1] = v.y;
    tile[kr][nc + 2] = v.z; tile[kr][nc + 3] = v.w;
  }
  __syncthreads();
  {
    int nr = t >> 3, kc = (t & 7) * 4;
    u16 h[4], l[4];
#pragma unroll
    for (int i = 0; i < 4; ++i) {
      float f = tile[kc + i][nr];
      h[i] = bf16_rne(f);
      l[i] = bf16_rne(f - bf16_to_f(h[i]));
    }
    size_t o = (size_t)(n0 + nr) * DM_ + k0 + kc;
    *(ushort4*)&Th[o] = make_ushort4(h[0], h[1], h[2], h[3]);
    *(ushort4*)&Tl[o] = make_ushort4(l[0], l[1], l[2], l[3]);
  }
}

// ---------------- K0b: x (4096x1024 f32) -> xh/xl bf16 (same layout)
__global__ __launch_bounds__(256) void xsplit_kernel(const float* __restrict__ x,
                                                     u16* __restrict__ xh,
                                                     u16* __restrict__ xl) {
  int gid = blockIdx.x * 256 + threadIdx.x;  // over BT_*DM_/4
  float4 v = *(const float4*)&x[(size_t)gid * 4];
  ushort4 h, l;
  h.x = bf16_rne(v.x); l.x = bf16_rne(v.x - bf16_to_f(h.x));
  h.y = bf16_rne(v.y); l.y = bf16_rne(v.y - bf16_to_f(h.y));
  h.z = bf16_rne(v.z); l.z = bf16_rne(v.z - bf16_to_f(h.z));
  h.w = bf16_rne(v.w); l.w = bf16_rne(v.w - bf16_to_f(h.w));
  *(ushort4*)&xh[(size_t)gid * 4] = h;
  *(ushort4*)&xl[(size_t)gid * 4] = l;
}

// ---------------- K1: xz = x @ W_in via split-bf16 MFMA, 128x256 tile, 8 waves.
// R5-proven structure: single 48KB LDS buffer, 3 blocks/CU, 2 barriers per K-step.
// z written as bf16 (feeds only vacc's elementwise product).
__global__ __launch_bounds__(512) void gemm1_mfma(const u16* __restrict__ Xh,
                                                  const u16* __restrict__ Xl,
                                                  const u16* __restrict__ Bh,
                                                  const u16* __restrict__ Bl,
                                                  float* __restrict__ xi,
                                                  u16* __restrict__ zb) {
  __shared__ __align__(16) char lds[49152];

  const int tid = threadIdx.x;
  const int m0 = blockIdx.x * 128;
  const int n0 = blockIdx.y * 256;
  const int wv = tid >> 6;
  const int lane = tid & 63;
  const int wr = wv >> 2, wc = wv & 3;     // 2 x 4 waves, each 64x64 out
  const int lrow = lane & 15, lk = lane >> 4;

  // per-wave staging: 6 chunks of 1KB each
  const u16* gbase[6];
  int ldsO[6];
  size_t goff[6];
#pragma unroll
  for (int i = 0; i < 6; ++i) {
    int c = wv * 6 + i;        // 0..47
    int O = c << 10;           // LDS byte offset
    int to;
    const u16* gb;
    if (O < 8192)       { gb = Xh + (size_t)m0 * DM_; to = O; }
    else if (O < 16384) { gb = Xl + (size_t)m0 * DM_; to = O - 8192; }
    else if (O < 32768) { gb = Bh + (size_t)n0 * DM_; to = O - 16384; }
    else                { gb = Bl + (size_t)n0 * DM_; to = O - 32768; }
    int r = (to >> 6) + (lane >> 2);
    int s_src = (lane & 3) ^ ((r >> 1) & 3);
    gbase[i] = gb;
    ldsO[i] = O;
    goff[i] = (size_t)r * DM_ + s_src * 8;
  }

  f32x4 acc[4][4];
#pragma unroll
  for (int i = 0; i < 4; ++i)
#pragma unroll
    for (int j = 0; j < 4; ++j) acc[i][j] = (f32x4){0.f, 0.f, 0.f, 0.f};

  for (int kk = 0; kk < DM_ / 32; ++kk) {
    const int k0 = kk * 32;
#pragma unroll
    for (int i = 0; i < 6; ++i) {
      gload_lds16(gbase[i] + goff[i] + k0, lds + ldsO[i]);
    }
    __syncthreads();  // drains vmcnt -> LDS tiles ready

    bf16x8 a_h[4], a_l[4], b_h[4], b_l[4];
#pragma unroll
    for (int mi = 0; mi < 4; ++mi) {
      int r = wr * 64 + mi * 16 + lrow;
      a_h[mi] = *(const bf16x8*)(lds + SWZ16(r, lk));
      a_l[mi] = *(const bf16x8*)(lds + 8192 + SWZ16(r, lk));
    }
#pragma unroll
    for (int ni = 0; ni < 4; ++ni) {
      int r = wc * 64 + ni * 16 + lrow;
      b_h[ni] = *(const bf16x8*)(lds + 16384 + SWZ16(r, lk));
      b_l[ni] = *(const bf16x8*)(lds + 32768 + SWZ16(r, lk));
    }
#pragma unroll
    for (int mi = 0; mi < 4; ++mi)
#pragma unroll
      for (int ni = 0; ni < 4; ++ni) {
        acc[mi][ni] = __builtin_amdgcn_mfma_f32_16x16x32_bf16(a_h[mi], b_h[ni], acc[mi][ni], 0, 0, 0);
        acc[mi][ni] = __builtin_amdgcn_mfma_f32_16x16x32_bf16(a_h[mi], b_l[ni], acc[mi][ni], 0, 0, 0);
        acc[mi][ni] = __builtin_amdgcn_mfma_f32_16x16x32_bf16(a_l[mi], b_h[ni], acc[mi][ni], 0, 0, 0);
      }
    __syncthreads();  // all waves done reading before next stage overwrites
  }

  const bool is_z = (n0 >= DI_);
#pragma unroll
  for (int mi = 0; mi < 4; ++mi) {
#pragma unroll
    for (int ni = 0; ni < 4; ++ni) {
      int mrow = m0 + wr * 64 + mi * 16 + (lane >> 4) * 4;
      int ncol = n0 + wc * 64 + ni * 16 + (lane & 15);
#pragma unroll
      for (int rg = 0; rg < 4; ++rg) {
        float v = acc[mi][ni][rg];
        int m = mrow + rg;
        if (!is_z) {
          xi[(size_t)m * DI_ + ncol] = v;
        } else {
          zb[(size_t)m * DI_ + (ncol - DI_)] = bf16_rne(silu_f(v));
        }
      }
    }
  }
}

// ---------------- K2: depthwise conv3 (pad 1) + bias + silu -> u (float4)
__global__ __launch_bounds__(256) void conv_silu_kernel(const float* __restrict__ xi,
                                                        const float* __restrict__ cw,
                                                        const float* __restrict__ cb,
                                                        float* __restrict__ u) {
  int gid = blockIdx.x * 256 + threadIdx.x;  // over B*L*DI/4
  int idx = gid * 4;
  int d = idx & (DI_ - 1);
  int t = (idx >> 11) & (L_ - 1);
  float4 xc = *(const float4*)&xi[idx];
  float4 xm = make_float4(0.f, 0.f, 0.f, 0.f);
  float4 xp = make_float4(0.f, 0.f, 0.f, 0.f);
  if (t > 0) xm = *(const float4*)&xi[idx - DI_];
  if (t < L_ - 1) xp = *(const float4*)&xi[idx + DI_];
  float4 o;
  {
    float w0 = cw[(d + 0) * 3], w1 = cw[(d + 0) * 3 + 1], w2 = cw[(d + 0) * 3 + 2];
    o.x = silu_f(cb[d + 0] + w0 * xm.x + w1 * xc.x + w2 * xp.x);
  }
  {
    float w0 = cw[(d + 1) * 3], w1 = cw[(d + 1) * 3 + 1], w2 = cw[(d + 1) * 3 + 2];
    o.y = silu_f(cb[d + 1] + w0 * xm.y + w1 * xc.y + w2 * xp.y);
  }
  {
    float w0 = cw[(d + 2) * 3], w1 = cw[(d + 2) * 3 + 1], w2 = cw[(d + 2) * 3 + 2];
    o.z = silu_f(cb[d + 2] + w0 * xm.z + w1 * xc.z + w2 * xp.z);
  }
  {
    float w0 = cw[(d + 3) * 3], w1 = cw[(d + 3) * 3 + 1], w2 = cw[(d + 3) * 3 + 2];
    o.w = silu_f(cb[d + 3] + w0 * xm.w + w1 * xc.w + w2 * xp.w);
  }
  *(float4*)&u[idx] = o;
}

// ---------------- K3a: W_x (2048x96 f32) -> Wx^T hi/lo bf16 (96 x 2048)
__global__ __launch_bounds__(256) void wxsplit_kernel(const float* __restrict__ Wx,
                                                      u16* __restrict__ Th,
                                                      u16* __restrict__ Tl) {
  int gid = blockIdx.x * 256 + threadIdx.x;  // over 96*2048
  int n = gid >> 11;
  int k = gid & (DI_ - 1);
  float f = Wx[(size_t)k * NX_ + n];
  u16 h = bf16_rne(f);
  Th[gid] = h;
  Tl[gid] = bf16_rne(f - bf16_to_f(h));
}

// ---------------- K3b: x_dbl partials via split-bf16 MFMA (plain stores to Pt).
__global__ __launch_bounds__(256) void xdbl_mfma(const float* __restrict__ U,
                                                 const u16* __restrict__ Wh,
                                                 const u16* __restrict__ Wl,
                                                 float* __restrict__ Pt) {
  __shared__ u16 Uh_s[128 * 32];
  __shared__ u16 Ul_s[128 * 32];
  __shared__ u16 Wh_s[96 * 32];
  __shared__ u16 Wl_s[96 * 32];

  const int tid = threadIdx.x;
  const int m0 = blockIdx.x * 128;
  const int kc = blockIdx.y;
  const int wv = tid >> 6;
  const int lane = tid & 63;
  const int lrow = lane & 15, lk = lane >> 4;
  const int ra = tid >> 1;
  const int hf = tid & 1;

  f32x4 acc[2][6];
#pragma unroll
  for (int i = 0; i < 2; ++i)
#pragma unroll
    for (int j = 0; j < 6; ++j) acc[i][j] = (f32x4){0.f, 0.f, 0.f, 0.f};

  float af[16];
  uint4 wh_r[3], wl_r[3];
  int wc_row[3], wc_slot[3], wc_buf[3];

  {
    int k0 = kc * KCL_;
    const float* up = &U[(size_t)(m0 + ra) * DI_ + k0 + hf * 16];
    float4 a0 = *(const float4*)(up + 0);
    float4 a1 = *(const float4*)(up + 4);
    float4 a2 = *(const float4*)(up + 8);
    float4 a3 = *(const float4*)(up + 12);
    af[0]=a0.x; af[1]=a0.y; af[2]=a0.z; af[3]=a0.w;
    af[4]=a1.x; af[5]=a1.y; af[6]=a1.z; af[7]=a1.w;
    af[8]=a2.x; af[9]=a2.y; af[10]=a2.z; af[11]=a2.w;
    af[12]=a3.x; af[13]=a3.y; af[14]=a3.z; af[15]=a3.w;
#pragma unroll
    for (int i = 0; i < 3; ++i) {
      int c = tid + 256 * i;
      int buf = c >= 384;
      int cc = c & 383;
      int row = cc >> 2, slot = cc & 3;
      wc_buf[i] = buf; wc_row[i] = row; wc_slot[i] = slot;
      const u16* src = (buf ? Wl : Wh) + (size_t)row * DI_ + k0 + slot * 8;
      uint4 v = *(const uint4*)src;
      if (buf) wl_r[i] = v; else wh_r[i] = v;
    }
  }

  for (int kk = 0; kk < KCL_ / 32; ++kk) {
    __syncthreads();
    {
      u16x8 hv0, hv1, lv0, lv1;
#pragma unroll
      for (int i = 0; i < 8; ++i) {
        u16 h = bf16_rne(af[i]);
        hv0[i] = h;
        lv0[i] = bf16_rne(af[i] - bf16_to_f(h));
      }
#pragma unroll
      for (int i = 0; i < 8; ++i) {
        u16 h = bf16_rne(af[8 + i]);
        hv1[i] = h;
        lv1[i] = bf16_rne(af[8 + i] - bf16_to_f(h));
      }
      int s0 = hf * 2;
      *(u16x8*)((char*)Uh_s + SWZ16(ra, s0)) = hv0;
      *(u16x8*)((char*)Uh_s + SWZ16(ra, s0 + 1)) = hv1;
      *(u16x8*)((char*)Ul_s + SWZ16(ra, s0)) = lv0;
      *(u16x8*)((char*)Ul_s + SWZ16(ra, s0 + 1)) = lv1;
#pragma unroll
      for (int i = 0; i < 3; ++i) {
        char* dst = (char*)(wc_buf[i] ? Wl_s : Wh_s) + SWZ16(wc_row[i], wc_slot[i]);
        *(uint4*)dst = wc_buf[i] ? wl_r[i] : wh_r[i];
      }
    }
    __syncthreads();

    if (kk + 1 < KCL_ / 32) {
      int k0 = kc * KCL_ + (kk + 1) * 32;
      const float* up = &U[(size_t)(m0 + ra) * DI_ + k0 + hf * 16];
      float4 a0 = *(const float4*)(up + 0);
      float4 a1 = *(const float4*)(up + 4);
      float4 a2 = *(const float4*)(up + 8);
      float4 a3 = *(const float4*)(up + 12);
      af[0]=a0.x; af[1]=a0.y; af[2]=a0.z; af[3]=a0.w;
      af[4]=a1.x; af[5]=a1.y; af[6]=a1.z; af[7]=a1.w;
      af[8]=a2.x; af[9]=a2.y; af[10]=a2.z; af[11]=a2.w;
      af[12]=a3.x; af[13]=a3.y; af[14]=a3.z; af[15]=a3.w;
#pragma unroll
      for (int i = 0; i < 3; ++i) {
        const u16* src = (wc_buf[i] ? Wl : Wh) + (size_t)wc_row[i] * DI_ + k0 + wc_slot[i] * 8;
        uint4 v = *(const uint4*)src;
        if (wc_buf[i]) wl_r[i] = v; else wh_r[i] = v;
      }
    }

    bf16x8 a_h[2], a_l[2], b_h[6], b_l[6];
#pragma unroll
    for (int mi = 0; mi < 2; ++mi) {
      int r = wv * 32 + mi * 16 + lrow;
      a_h[mi] = *(const bf16x8*)((const char*)Uh_s + SWZ16(r, lk));
      a_l[mi] = *(const bf16x8*)((const char*)Ul_s + SWZ16(r, lk));
    }
#pragma unroll
    for (int ni = 0; ni < 6; ++ni) {
      int r = ni * 16 + lrow;
      b_h[ni] = *(const bf16x8*)((const char*)Wh_s + SWZ16(r, lk));
      b_l[ni] = *(const bf16x8*)((const char*)Wl_s + SWZ16(r, lk));
    }
#pragma unroll
    for (int mi = 0; mi < 2; ++mi)
#pragma unroll
      for (int ni = 0; ni < 6; ++ni) {
        acc[mi][ni] = __builtin_amdgcn_mfma_f32_16x16x32_bf16(a_h[mi], b_h[ni], acc[mi][ni], 0, 0, 0);
        acc[mi][ni] = __builtin_amdgcn_mfma_f32_16x16x32_bf16(a_h[mi], b_l[ni], acc[mi][ni], 0, 0, 0);
        acc[mi][ni] = __builtin_amdgcn_mfma_f32_16x16x32_bf16(a_l[mi], b_h[ni], acc[mi][ni], 0, 0, 0);
      }
  }

#pragma unroll
  for (int mi = 0; mi < 2; ++mi) {
#pragma unroll
    for (int ni = 0; ni < 6; ++ni) {
      int mrow = m0 + wv * 32 + mi * 16 + (lane >> 4) * 4;
      int ncol = ni * 16 + (lane & 15);
#pragma unroll
      for (int rg = 0; rg < 4; ++rg) {
        Pt[((size_t)kc * BT_ + mrow + rg) * NX_ + ncol] = acc[mi][ni][rg];
      }
    }
  }
}

// ---------------- K4 (fused): reduce Pt chunks -> xdbl (LDS + global) -> delta
__global__ __launch_bounds__(256) void xdbl_delta_kernel(const float* __restrict__ Pt,
                                                         float* __restrict__ xdbl,
                                                         const float* __restrict__ Wdt,
                                                         const float* __restrict__ dtb,
                                                         float* __restrict__ delta) {
  __shared__ float xs[8][NX_];
  const int m0 = blockIdx.x * 8;
  const int tid = threadIdx.x;
  // reduce the 8 K-chunk partials for 8 rows x 96 cols
  for (int i = tid; i < 8 * NX_; i += 256) {
    int mi = i / NX_, ccol = i - mi * NX_;
    size_t off = (size_t)(m0 + mi) * NX_ + ccol;
    float s = 0.f;
#pragma unroll
    for (int kc = 0; kc < KC_; ++kc) s += Pt[(size_t)kc * BT_ * NX_ + off];
    xs[mi][ccol] = s;
    xdbl[off] = s;
  }
  __syncthreads();

  float acc[8][8];
#pragma unroll
  for (int mi = 0; mi < 8; ++mi)
#pragma unroll
    for (int j = 0; j < 8; ++j) acc[mi][j] = 0.f;

  for (int r = 0; r < R_; ++r) {
    float wd[8];
#pragma unroll
    for (int j = 0; j < 8; ++j) wd[j] = Wdt[(size_t)r * DI_ + tid + j * 256];
#pragma unroll
    for (int mi = 0; mi < 8; ++mi) {
      float xr = xs[mi][r];
#pragma unroll
      for (int j = 0; j < 8; ++j) acc[mi][j] += xr * wd[j];
    }
  }
#pragma unroll
  for (int j = 0; j < 8; ++j) {
    int d = tid + j * 256;
    float bias = dtb[d];
#pragma unroll
    for (int mi = 0; mi < 8; ++mi) {
      delta[(size_t)(m0 + mi) * DI_ + d] = softplus_f(acc[mi][j] + bias);
    }
  }
}

// ---------------- K5a: chunk scan, 4 lanes/channel x 4 states/lane -> (P, Q)
// Ac2 pre-folds log2(e): exp(dt*Ac) == exp2(dt*Ac2), one v_mul fewer per exp.
__global__ __launch_bounds__(256) void scanA_kernel(const float* __restrict__ delta,
                                                    const float* __restrict__ u,
                                                    const float* __restrict__ xdbl,
                                                    const float* __restrict__ A_logs,
                                                    float* __restrict__ P,
                                                    float* __restrict__ Q) {
  const int tid = threadIdx.x;
  const int q = tid & 3;                    // n-quad
  const int chan = blockIdx.x * 64 + (tid >> 2);
  const int c = blockIdx.y;
  const int b = chan >> 11;
  const int d = chan & (DI_ - 1);
  float Ac2[4];
#pragma unroll
  for (int j = 0; j < 4; ++j) Ac2[j] = -expf(A_logs[d * N_ + q * 4 + j]) * LOG2E_;
  const size_t base = (size_t)b * L_ * DI_ + d;
  const float* xd = xdbl + (size_t)b * L_ * NX_;
  float h[4] = {0.f, 0.f, 0.f, 0.f};
  float sdt = 0.f;
  const int t0 = c * LC_;
  for (int tt = 0; tt < LC_; ++tt) {
    int t = t0 + tt;
    float dt = delta[base + (size_t)t * DI_];
    float ut = u[base + (size_t)t * DI_];
    float4 Bt = *(const float4*)&xd[t * NX_ + R_ + q * 4];
    float du = dt * ut;
    float e0 = exp2f(dt * Ac2[0]), e1 = exp2f(dt * Ac2[1]);
    float e2 = exp2f(dt * Ac2[2]), e3 = exp2f(dt * Ac2[3]);
    h[0] = e0 * h[0] + du * Bt.x;
    h[1] = e1 * h[1] + du * Bt.y;
    h[2] = e2 * h[2] + du * Bt.z;
    h[3] = e3 * h[3] + du * Bt.w;
    sdt += dt;
  }
  size_t idx = ((size_t)chan * CH_ + c) * N_ + q * 4;
  *(float4*)&P[idx] = make_float4(exp2f(Ac2[0] * sdt), exp2f(Ac2[1] * sdt),
                                  exp2f(Ac2[2] * sdt), exp2f(Ac2[3] * sdt));
  *(float4*)&Q[idx] = make_float4(h[0], h[1], h[2], h[3]);
}

// ---------------- K5b: sequential combine over chunks -> H0
__global__ __launch_bounds__(256) void scanB_kernel(const float* __restrict__ P,
                                                    const float* __restrict__ Q,
                                                    float* __restrict__ H0) {
  int gid = blockIdx.x * 256 + threadIdx.x;  // over B*DI*N = 131072
  int chan = gid >> 4;
  int n = gid & 15;
  float h = 0.f;
  for (int c = 0; c < CH_; ++c) {
    size_t idx = ((size_t)chan * CH_ + c) * N_ + n;
    H0[idx] = h;
    h = P[idx] * h + Q[idx];
  }
}

// ---------------- K5c: replay with true initial state; y in-place over u
__global__ __launch_bounds__(256) void scanC_kernel(const float* __restrict__ delta,
                                                    float* uy,  // u in, y out (aliased)
                                                    const float* __restrict__ xdbl,
                                                    const float* __restrict__ A_logs,
                                                    const float* __restrict__ Ds,
                                                    const float* __restrict__ H0) {
  const int tid = threadIdx.x;
  const int q = tid & 3;
  const int chan = blockIdx.x * 64 + (tid >> 2);
  const int c = blockIdx.y;
  const int b = chan >> 11;
  const int d = chan & (DI_ - 1);
  float Ac2[4];
#pragma unroll
  for (int j = 0; j < 4; ++j) Ac2[j] = -expf(A_logs[d * N_ + q * 4 + j]) * LOG2E_;
  const float Dd = Ds[d];
  const size_t base = (size_t)b * L_ * DI_ + d;
  const float* dl = delta + base;
  float* ul = uy + base;
  const float* xd = xdbl + (size_t)b * L_ * NX_;
  float h[4];
  {
    float4 h0 = *(const float4*)&H0[((size_t)chan * CH_ + c) * N_ + q * 4];
    h[0] = h0.x; h[1] = h0.y; h[2] = h0.z; h[3] = h0.w;
  }
  const int t0 = c * LC_;
  for (int tt = 0; tt < LC_; ++tt) {
    int t = t0 + tt;
    float dt = dl[(size_t)t * DI_];
    float ut = ul[(size_t)t * DI_];
    float4 Bt = *(const float4*)&xd[t * NX_ + R_ + q * 4];
    float4 Ct = *(const float4*)&xd[t * NX_ + R_ + N_ + q * 4];
    float du = dt * ut;
    float e0 = exp2f(dt * Ac2[0]), e1 = exp2f(dt * Ac2[1]);
    float e2 = exp2f(dt * Ac2[2]), e3 = exp2f(dt * Ac2[3]);
    h[0] = e0 * h[0] + du * Bt.x;
    h[1] = e1 * h[1] + du * Bt.y;
    h[2] = e2 * h[2] + du * Bt.z;
    h[3] = e3 * h[3] + du * Bt.w;
    float p = h[0] * Ct.x + h[1] * Ct.y + h[2] * Ct.z + h[3] * Ct.w;
    p += __shfl_xor(p, 1);
    p += __shfl_xor(p, 2);
    if (q == 0) ul[(size_t)t * DI_] = p + Dd * ut;
  }
}

// ---------------- K6: per-row mean / rstd over DI
__global__ __launch_bounds__(256) void stats_kernel(const float* __restrict__ y,
                                                    float* __restrict__ mu,
                                                    float* __restrict__ rs) {
  __shared__ float red[4];
  const int row = blockIdx.x;
  const float* yr = y + (size_t)row * DI_;
  const int tid = threadIdx.x;
  float v[8];
  float s = 0.f;
#pragma unroll
  for (int j = 0; j < 8; ++j) { v[j] = yr[tid + j * 256]; s += v[j]; }
#pragma unroll
  for (int o = 1; o < 64; o <<= 1) s += __shfl_xor(s, o);
  if ((tid & 63) == 0) red[tid >> 6] = s;
  __syncthreads();
  float mu_v = (red[0] + red[1] + red[2] + red[3]) * (1.f / DI_);
  float q = 0.f;
#pragma unroll
  for (int j = 0; j < 8; ++j) { float dd = v[j] - mu_v; q += dd * dd; }
#pragma unroll
  for (int o = 1; o < 64; o <<= 1) q += __shfl_xor(q, o);
  __syncthreads();
  if ((tid & 63) == 0) red[tid >> 6] = q;
  __syncthreads();
  if (tid == 0) {
    float var = (red[0] + red[1] + red[2] + red[3]) * (1.f / DI_);
    mu[row] = mu_v;
    rs[row] = rsqrtf(var + 1e-5f);
  }
}

// ---------------- K7: v[b,d] = mean_t( ln(y)*z ), float4 y + bf16x4 z
__global__ __launch_bounds__(256) void vacc_kernel(const float* __restrict__ y,
                                                   const u16* __restrict__ zb,
                                                   const float* __restrict__ mu,
                                                   const float* __restrict__ rs,
                                                   const float* __restrict__ g,
                                                   const float* __restrict__ bb,
                                                   float* __restrict__ v) {
  const int d = (blockIdx.x * 256 + threadIdx.x) * 4;  // grid.x = DI/1024
  const int t0 = blockIdx.y * 16;                      // grid.y = L/16
  const int b = blockIdx.z;
  float4 gg = *(const float4*)&g[d];
  float4 bv = *(const float4*)&bb[d];
  float4 acc = make_float4(0.f, 0.f, 0.f, 0.f);
  for (int tt = 0; tt < 16; ++tt) {
    int row = b * L_ + t0 + tt;
    float4 yv = *(const float4*)&y[(size_t)row * DI_ + d];
    ushort4 zv = *(const ushort4*)&zb[(size_t)row * DI_ + d];
    float m = mu[row], r = rs[row];
    acc.x += ((yv.x - m) * r * gg.x + bv.x) * bf16_to_f(zv.x);
    acc.y += ((yv.y - m) * r * gg.y + bv.y) * bf16_to_f(zv.y);
    acc.z += ((yv.z - m) * r * gg.z + bv.z) * bf16_to_f(zv.z);
    acc.w += ((yv.w - m) * r * gg.w + bv.w) * bf16_to_f(zv.w);
  }
  atomicAdd(&v[b * DI_ + d + 0], acc.x * (1.f / L_));
  atomicAdd(&v[b * DI_ + d + 1], acc.y * (1.f / L_));
  atomicAdd(&v[b * DI_ + d + 2], acc.z * (1.f / L_));
  atomicAdd(&v[b * DI_ + d + 3], acc.w * (1.f / L_));
}

// ---------------- K8: out init = b_out
__global__ __launch_bounds__(256) void outinit_kernel(const float* __restrict__ b_out,
                                                      float* __restrict__ out) {
  int i = blockIdx.x * 256 + threadIdx.x;  // 0..4095
  out[i] = b_out[i & (DM_ - 1)];
}

// ---------------- K9: out += v @ W_out (partial over d-chunks, atomic)
__global__ __launch_bounds__(256) void outgemm_kernel(const float* __restrict__ v,
                                                      const float* __restrict__ Wout,
                                                      float* __restrict__ out) {
  const int m = blockIdx.x * 256 + threadIdx.x;  // 0..1023
  const int d0 = blockIdx.y * 128;
  float a0 = 0.f, a1 = 0.f, a2 = 0.f, a3 = 0.f;
  for (int dd = 0; dd < 128; ++dd) {
    float w = Wout[(size_t)(d0 + dd) * DM_ + m];
    a0 += v[0 * DI_ + d0 + dd] * w;
    a1 += v[1 * DI_ + d0 + dd] * w;
    a2 += v[2 * DI_ + d0 + dd] * w;
    a3 += v[3 * DI_ + d0 + dd] * w;
  }
  atomicAdd(&out[0 * DM_ + m], a0);
  atomicAdd(&out[1 * DM_ + m], a1);
  atomicAdd(&out[2 * DM_ + m], a2);
  atomicAdd(&out[3 * DM_ + m], a3);
}

extern "C" void kernel_launch(void* const* d_in, const int* in_sizes, int n_in,
                              void* d_out, int out_size, void* d_ws, size_t ws_size,
                              hipStream_t stream) {
  const float* x      = (const float*)d_in[0];
  const float* W_in   = (const float*)d_in[1];
  const float* conv_w = (const float*)d_in[2];
  const float* conv_b = (const float*)d_in[3];
  const float* W_x    = (const float*)d_in[4];
  const float* W_dt   = (const float*)d_in[5];
  const float* dt_bias= (const float*)d_in[6];
  const float* A_logs = (const float*)d_in[7];
  const float* Ds     = (const float*)d_in[8];
  const float* ln_g   = (const float*)d_in[9];
  const float* ln_b   = (const float*)d_in[10];
  const float* W_out  = (const float*)d_in[11];
  const float* b_out  = (const float*)d_in[12];
  float* out = (float*)d_out;

  float* ws = (float*)d_ws;
  const size_t BIG = (size_t)BT_ * DI_;          // 8,388,608 floats
  float* xi_buf   = ws;                          // xi; later delta
  float* z_buf    = ws + BIG;                    // silu(z) as bf16
  float* u_buf    = ws + 2 * BIG;                // xh/xl pre-split, then u, later y (in-place)
  float* xdbl_buf = ws + 3 * BIG;                // 4096*96
  float* mu_buf   = xdbl_buf + (size_t)BT_ * NX_;
  float* rs_buf   = mu_buf + BT_;
  float* v_buf    = rs_buf + BT_;                // B*DI
  float* P_buf    = v_buf + (size_t)B_ * DI_;    // B*DI*CH*N = 2,097,152 floats
  float* Q_buf    = P_buf + (size_t)B_ * DI_ * CH_ * N_;
  float* H0_buf   = Q_buf + (size_t)B_ * DI_ * CH_ * N_;

  u16* wt_hi = (u16*)P_buf;                      // W_in^T hi/lo (dead after gemm1)
  u16* wt_lo = (u16*)Q_buf;
  u16* wx_hi = (u16*)H0_buf;                     // Wx^T hi/lo (dead until scanB)
  u16* wx_lo = wx_hi + (size_t)NX_ * DI_;
  u16* xh = (u16*)u_buf;                         // x hi/lo (dead until conv writes u)
  u16* xl = xh + (size_t)BT_ * DM_;
  u16* zb = (u16*)z_buf;                         // z as bf16
  // Pt (8 x 4096 x 96 = 12.6 MB) spans P_buf+Q_buf (16.8 MB) — wt dead after
  // gemm1; P/Q written by scanA only after xdbl_delta consumes Pt.
  float* xdbl_part = P_buf;

  hipMemsetAsync(v_buf, 0, (size_t)B_ * DI_ * sizeof(float), stream);

  wsplit_kernel<<<dim3((2 * DI_) / 32, DM_ / 32), 256, 0, stream>>>(W_in, wt_hi, wt_lo);
  xsplit_kernel<<<(BT_ * DM_) / 1024, 256, 0, stream>>>(x, xh, xl);
  gemm1_mfma<<<dim3(BT_ / 128, (2 * DI_) / 256), 512, 0, stream>>>(xh, xl, wt_hi, wt_lo,
                                                                   xi_buf, zb);
  conv_silu_kernel<<<(BT_ * DI_) / 1024, 256, 0, stream>>>(xi_buf, conv_w, conv_b, u_buf);
  wxsplit_kernel<<<(NX_ * DI_) / 256, 256, 0, stream>>>(W_x, wx_hi, wx_lo);
  xdbl_mfma<<<dim3(BT_ / 128, KC_), 256, 0, stream>>>(u_buf, wx_hi, wx_lo, xdbl_part);
  xdbl_delta_kernel<<<BT_ / 8, 256, 0, stream>>>(xdbl_part, xdbl_buf, W_dt, dt_bias, xi_buf);
  scanA_kernel<<<dim3((B_ * DI_) / 64, CH_), 256, 0, stream>>>(xi_buf, u_buf, xdbl_buf,
                                                               A_logs, P_buf, Q_buf);
  scanB_kernel<<<(B_ * DI_ * N_) / 256, 256, 0, stream>>>(P_buf, Q_buf, H0_buf);
  scanC_kernel<<<dim3((B_ * DI_) / 64, CH_), 256, 0, stream>>>(xi_buf, u_buf, xdbl_buf,
                                                               A_logs, Ds, H0_buf);
  stats_kernel<<<BT_, 256, 0, stream>>>(u_buf, mu_buf, rs_buf);
  vacc_kernel<<<dim3(DI_ / 1024, L_ / 16, B_), 256, 0, stream>>>(u_buf, zb, mu_buf, rs_buf,
                                                                 ln_g, ln_b, v_buf);
  outinit_kernel<<<(B_ * DM_) / 256, 256, 0, stream>>>(b_out, out);
  outgemm_kernel<<<dim3(DM_ / 256, DI_ / 128), 256, 0, stream>>>(v_buf, W_out, out);
}

// Round 14
// 332.931 us; speedup vs baseline: 1.0655x; 1.0655x over previous
//
#include <hip/hip_runtime.h>
#include <math.h>

#define B_ 4
#define L_ 1024
#define DM_ 1024
#define DI_ 2048
#define N_ 16
#define R_ 64
#define BT_ (B_*L_)   // 4096 tokens
#define NX_ 96        // R + 2N
#define CH_ 16        // scan chunks
#define LC_ (L_/CH_)  // 64 steps per chunk
#define KC_ 8         // xdbl k-chunks
#define KCL_ (DI_/KC_)// 256 k per chunk

typedef unsigned short u16;
typedef unsigned int u32;
typedef short bf16x8 __attribute__((ext_vector_type(8)));
typedef u16 u16x8 __attribute__((ext_vector_type(8)));
typedef float f32x4 __attribute__((ext_vector_type(4)));

__device__ __forceinline__ float silu_f(float x) { return x / (1.f + expf(-x)); }
__device__ __forceinline__ float softplus_f(float x) {
  return x > 0.f ? x + log1pf(expf(-x)) : log1pf(expf(x));
}
__device__ __forceinline__ u16 bf16_rne(float f) {
  u32 u = __float_as_uint(f);
  u32 r = (u + 0x7FFFu + ((u >> 16) & 1u)) >> 16;
  return (u16)r;
}
__device__ __forceinline__ float bf16_to_f(u16 h) {
  return __uint_as_float(((u32)h) << 16);
}
__device__ __forceinline__ void gload_lds16(const void* g, void* l) {
  __builtin_amdgcn_global_load_lds((const __attribute__((address_space(1))) void*)g,
                                   (__attribute__((address_space(3))) void*)l, 16, 0, 0);
}

// swizzled byte offset within a [rows][32] u16 tile (64B rows, 16B granules)
#define SWZ16(r, s) ((r) * 64 + ((((s) ^ (((r) >> 1) & 3))) << 4))

// ---------------- K0a: W_in (1024x4096 f32) -> Wt_hi/Wt_lo (4096x1024 bf16), transposed split
__global__ __launch_bounds__(256) void wsplit_kernel(const float* __restrict__ W,
                                                     u16* __restrict__ Th,
                                                     u16* __restrict__ Tl) {
  __shared__ float tile[32][33];
  const int n0 = blockIdx.x * 32;
  const int k0 = blockIdx.y * 32;
  const int t = threadIdx.x;
  {
    int kr = t >> 3, nc = (t & 7) * 4;
    float4 v = *(const float4*)&W[(size_t)(k0 + kr) * (2 * DI_) + n0 + nc];
    tile[kr][nc + 0] = v.x; tile[kr][nc + 1] = v.y;
    tile[kr][nc + 2] = v.z; tile[kr][nc + 3] = v.w;
  }
  __syncthreads();
  {
    int nr = t >> 3, kc = (t & 7) * 4;
    u16 h[4], l[4];
#pragma unroll
    for (int i = 0; i < 4; ++i) {
      float f = tile[kc + i][nr];
      h[i] = bf16_rne(f);
      l[i] = bf16_rne(f - bf16_to_f(h[i]));
    }
    size_t o = (size_t)(n0 + nr) * DM_ + k0 + kc;
    *(ushort4*)&Th[o] = make_ushort4(h[0], h[1], h[2], h[3]);
    *(ushort4*)&Tl[o] = make_ushort4(l[0], l[1], l[2], l[3]);
  }
}

// ---------------- K0b: x (4096x1024 f32) -> xh/xl bf16 (same layout)
__global__ __launch_bounds__(256) void xsplit_kernel(const float* __restrict__ x,
                                                     u16* __restrict__ xh,
                                                     u16* __restrict__ xl) {
  int gid = blockIdx.x * 256 + threadIdx.x;  // over BT_*DM_/4
  float4 v = *(const float4*)&x[(size_t)gid * 4];
  ushort4 h, l;
  h.x = bf16_rne(v.x); l.x = bf16_rne(v.x - bf16_to_f(h.x));
  h.y = bf16_rne(v.y); l.y = bf16_rne(v.y - bf16_to_f(h.y));
  h.z = bf16_rne(v.z); l.z = bf16_rne(v.z - bf16_to_f(h.z));
  h.w = bf16_rne(v.w); l.w = bf16_rne(v.w - bf16_to_f(h.w));
  *(ushort4*)&xh[(size_t)gid * 4] = h;
  *(ushort4*)&xl[(size_t)gid * 4] = l;
}

// ---------------- K1: xz = x @ W_in via split-bf16 MFMA, 128x256 tile, 8 waves.
// R5-proven structure: single 48KB LDS buffer, 3 blocks/CU, 2 barriers per K-step.
// z written as bf16 (feeds only vacc's elementwise product).
__global__ __launch_bounds__(512) void gemm1_mfma(const u16* __restrict__ Xh,
                                                  const u16* __restrict__ Xl,
                                                  const u16* __restrict__ Bh,
                                                  const u16* __restrict__ Bl,
                                                  float* __restrict__ xi,
                                                  u16* __restrict__ zb) {
  __shared__ __align__(16) char lds[49152];

  const int tid = threadIdx.x;
  const int m0 = blockIdx.x * 128;
  const int n0 = blockIdx.y * 256;
  const int wv = tid >> 6;
  const int lane = tid & 63;
  const int wr = wv >> 2, wc = wv & 3;     // 2 x 4 waves, each 64x64 out
  const int lrow = lane & 15, lk = lane >> 4;

  // per-wave staging: 6 chunks of 1KB each
  const u16* gbase[6];
  int ldsO[6];
  size_t goff[6];
#pragma unroll
  for (int i = 0; i < 6; ++i) {
    int c = wv * 6 + i;        // 0..47
    int O = c << 10;           // LDS byte offset
    int to;
    const u16* gb;
    if (O < 8192)       { gb = Xh + (size_t)m0 * DM_; to = O; }
    else if (O < 16384) { gb = Xl + (size_t)m0 * DM_; to = O - 8192; }
    else if (O < 32768) { gb = Bh + (size_t)n0 * DM_; to = O - 16384; }
    else                { gb = Bl + (size_t)n0 * DM_; to = O - 32768; }
    int r = (to >> 6) + (lane >> 2);
    int s_src = (lane & 3) ^ ((r >> 1) & 3);
    gbase[i] = gb;
    ldsO[i] = O;
    goff[i] = (size_t)r * DM_ + s_src * 8;
  }

  f32x4 acc[4][4];
#pragma unroll
  for (int i = 0; i < 4; ++i)
#pragma unroll
    for (int j = 0; j < 4; ++j) acc[i][j] = (f32x4){0.f, 0.f, 0.f, 0.f};

  for (int kk = 0; kk < DM_ / 32; ++kk) {
    const int k0 = kk * 32;
#pragma unroll
    for (int i = 0; i < 6; ++i) {
      gload_lds16(gbase[i] + goff[i] + k0, lds + ldsO[i]);
    }
    __syncthreads();  // drains vmcnt -> LDS tiles ready

    bf16x8 a_h[4], a_l[4], b_h[4], b_l[4];
#pragma unroll
    for (int mi = 0; mi < 4; ++mi) {
      int r = wr * 64 + mi * 16 + lrow;
      a_h[mi] = *(const bf16x8*)(lds + SWZ16(r, lk));
      a_l[mi] = *(const bf16x8*)(lds + 8192 + SWZ16(r, lk));
    }
#pragma unroll
    for (int ni = 0; ni < 4; ++ni) {
      int r = wc * 64 + ni * 16 + lrow;
      b_h[ni] = *(const bf16x8*)(lds + 16384 + SWZ16(r, lk));
      b_l[ni] = *(const bf16x8*)(lds + 32768 + SWZ16(r, lk));
    }
#pragma unroll
    for (int mi = 0; mi < 4; ++mi)
#pragma unroll
      for (int ni = 0; ni < 4; ++ni) {
        acc[mi][ni] = __builtin_amdgcn_mfma_f32_16x16x32_bf16(a_h[mi], b_h[ni], acc[mi][ni], 0, 0, 0);
        acc[mi][ni] = __builtin_amdgcn_mfma_f32_16x16x32_bf16(a_h[mi], b_l[ni], acc[mi][ni], 0, 0, 0);
        acc[mi][ni] = __builtin_amdgcn_mfma_f32_16x16x32_bf16(a_l[mi], b_h[ni], acc[mi][ni], 0, 0, 0);
      }
    __syncthreads();  // all waves done reading before next stage overwrites
  }

  const bool is_z = (n0 >= DI_);
#pragma unroll
  for (int mi = 0; mi < 4; ++mi) {
#pragma unroll
    for (int ni = 0; ni < 4; ++ni) {
      int mrow = m0 + wr * 64 + mi * 16 + (lane >> 4) * 4;
      int ncol = n0 + wc * 64 + ni * 16 + (lane & 15);
#pragma unroll
      for (int rg = 0; rg < 4; ++rg) {
        float v = acc[mi][ni][rg];
        int m = mrow + rg;
        if (!is_z) {
          xi[(size_t)m * DI_ + ncol] = v;
        } else {
          zb[(size_t)m * DI_ + (ncol - DI_)] = bf16_rne(silu_f(v));
        }
      }
    }
  }
}

// ---------------- K2: depthwise conv3 (pad 1) + bias + silu -> u (float4)
__global__ __launch_bounds__(256) void conv_silu_kernel(const float* __restrict__ xi,
                                                        const float* __restrict__ cw,
                                                        const float* __restrict__ cb,
                                                        float* __restrict__ u) {
  int gid = blockIdx.x * 256 + threadIdx.x;  // over B*L*DI/4
  int idx = gid * 4;
  int d = idx & (DI_ - 1);
  int t = (idx >> 11) & (L_ - 1);
  float4 xc = *(const float4*)&xi[idx];
  float4 xm = make_float4(0.f, 0.f, 0.f, 0.f);
  float4 xp = make_float4(0.f, 0.f, 0.f, 0.f);
  if (t > 0) xm = *(const float4*)&xi[idx - DI_];
  if (t < L_ - 1) xp = *(const float4*)&xi[idx + DI_];
  float4 o;
  {
    float w0 = cw[(d + 0) * 3], w1 = cw[(d + 0) * 3 + 1], w2 = cw[(d + 0) * 3 + 2];
    o.x = silu_f(cb[d + 0] + w0 * xm.x + w1 * xc.x + w2 * xp.x);
  }
  {
    float w0 = cw[(d + 1) * 3], w1 = cw[(d + 1) * 3 + 1], w2 = cw[(d + 1) * 3 + 2];
    o.y = silu_f(cb[d + 1] + w0 * xm.y + w1 * xc.y + w2 * xp.y);
  }
  {
    float w0 = cw[(d + 2) * 3], w1 = cw[(d + 2) * 3 + 1], w2 = cw[(d + 2) * 3 + 2];
    o.z = silu_f(cb[d + 2] + w0 * xm.z + w1 * xc.z + w2 * xp.z);
  }
  {
    float w0 = cw[(d + 3) * 3], w1 = cw[(d + 3) * 3 + 1], w2 = cw[(d + 3) * 3 + 2];
    o.w = silu_f(cb[d + 3] + w0 * xm.w + w1 * xc.w + w2 * xp.w);
  }
  *(float4*)&u[idx] = o;
}

// ---------------- K3a: W_x (2048x96 f32) -> Wx^T hi/lo bf16 (96 x 2048)
__global__ __launch_bounds__(256) void wxsplit_kernel(const float* __restrict__ Wx,
                                                      u16* __restrict__ Th,
                                                      u16* __restrict__ Tl) {
  int gid = blockIdx.x * 256 + threadIdx.x;  // over 96*2048
  int n = gid >> 11;
  int k = gid & (DI_ - 1);
  float f = Wx[(size_t)k * NX_ + n];
  u16 h = bf16_rne(f);
  Th[gid] = h;
  Tl[gid] = bf16_rne(f - bf16_to_f(h));
}

// ---------------- K3b: x_dbl partials via split-bf16 MFMA (plain stores to Pt).
__global__ __launch_bounds__(256) void xdbl_mfma(const float* __restrict__ U,
                                                 const u16* __restrict__ Wh,
                                                 const u16* __restrict__ Wl,
                                                 float* __restrict__ Pt) {
  __shared__ u16 Uh_s[128 * 32];
  __shared__ u16 Ul_s[128 * 32];
  __shared__ u16 Wh_s[96 * 32];
  __shared__ u16 Wl_s[96 * 32];

  const int tid = threadIdx.x;
  const int m0 = blockIdx.x * 128;
  const int kc = blockIdx.y;
  const int wv = tid >> 6;
  const int lane = tid & 63;
  const int lrow = lane & 15, lk = lane >> 4;
  const int ra = tid >> 1;
  const int hf = tid & 1;

  f32x4 acc[2][6];
#pragma unroll
  for (int i = 0; i < 2; ++i)
#pragma unroll
    for (int j = 0; j < 6; ++j) acc[i][j] = (f32x4){0.f, 0.f, 0.f, 0.f};

  float af[16];
  uint4 wh_r[3], wl_r[3];
  int wc_row[3], wc_slot[3], wc_buf[3];

  {
    int k0 = kc * KCL_;
    const float* up = &U[(size_t)(m0 + ra) * DI_ + k0 + hf * 16];
    float4 a0 = *(const float4*)(up + 0);
    float4 a1 = *(const float4*)(up + 4);
    float4 a2 = *(const float4*)(up + 8);
    float4 a3 = *(const float4*)(up + 12);
    af[0]=a0.x; af[1]=a0.y; af[2]=a0.z; af[3]=a0.w;
    af[4]=a1.x; af[5]=a1.y; af[6]=a1.z; af[7]=a1.w;
    af[8]=a2.x; af[9]=a2.y; af[10]=a2.z; af[11]=a2.w;
    af[12]=a3.x; af[13]=a3.y; af[14]=a3.z; af[15]=a3.w;
#pragma unroll
    for (int i = 0; i < 3; ++i) {
      int c = tid + 256 * i;
      int buf = c >= 384;
      int cc = c & 383;
      int row = cc >> 2, slot = cc & 3;
      wc_buf[i] = buf; wc_row[i] = row; wc_slot[i] = slot;
      const u16* src = (buf ? Wl : Wh) + (size_t)row * DI_ + k0 + slot * 8;
      uint4 v = *(const uint4*)src;
      if (buf) wl_r[i] = v; else wh_r[i] = v;
    }
  }

  for (int kk = 0; kk < KCL_ / 32; ++kk) {
    __syncthreads();
    {
      u16x8 hv0, hv1, lv0, lv1;
#pragma unroll
      for (int i = 0; i < 8; ++i) {
        u16 h = bf16_rne(af[i]);
        hv0[i] = h;
        lv0[i] = bf16_rne(af[i] - bf16_to_f(h));
      }
#pragma unroll
      for (int i = 0; i < 8; ++i) {
        u16 h = bf16_rne(af[8 + i]);
        hv1[i] = h;
        lv1[i] = bf16_rne(af[8 + i] - bf16_to_f(h));
      }
      int s0 = hf * 2;
      *(u16x8*)((char*)Uh_s + SWZ16(ra, s0)) = hv0;
      *(u16x8*)((char*)Uh_s + SWZ16(ra, s0 + 1)) = hv1;
      *(u16x8*)((char*)Ul_s + SWZ16(ra, s0)) = lv0;
      *(u16x8*)((char*)Ul_s + SWZ16(ra, s0 + 1)) = lv1;
#pragma unroll
      for (int i = 0; i < 3; ++i) {
        char* dst = (char*)(wc_buf[i] ? Wl_s : Wh_s) + SWZ16(wc_row[i], wc_slot[i]);
        *(uint4*)dst = wc_buf[i] ? wl_r[i] : wh_r[i];
      }
    }
    __syncthreads();

    if (kk + 1 < KCL_ / 32) {
      int k0 = kc * KCL_ + (kk + 1) * 32;
      const float* up = &U[(size_t)(m0 + ra) * DI_ + k0 + hf * 16];
      float4 a0 = *(const float4*)(up + 0);
      float4 a1 = *(const float4*)(up + 4);
      float4 a2 = *(const float4*)(up + 8);
      float4 a3 = *(const float4*)(up + 12);
      af[0]=a0.x; af[1]=a0.y; af[2]=a0.z; af[3]=a0.w;
      af[4]=a1.x; af[5]=a1.y; af[6]=a1.z; af[7]=a1.w;
      af[8]=a2.x; af[9]=a2.y; af[10]=a2.z; af[11]=a2.w;
      af[12]=a3.x; af[13]=a3.y; af[14]=a3.z; af[15]=a3.w;
#pragma unroll
      for (int i = 0; i < 3; ++i) {
        const u16* src = (wc_buf[i] ? Wl : Wh) + (size_t)wc_row[i] * DI_ + k0 + wc_slot[i] * 8;
        uint4 v = *(const uint4*)src;
        if (wc_buf[i]) wl_r[i] = v; else wh_r[i] = v;
      }
    }

    bf16x8 a_h[2], a_l[2], b_h[6], b_l[6];
#pragma unroll
    for (int mi = 0; mi < 2; ++mi) {
      int r = wv * 32 + mi * 16 + lrow;
      a_h[mi] = *(const bf16x8*)((const char*)Uh_s + SWZ16(r, lk));
      a_l[mi] = *(const bf16x8*)((const char*)Ul_s + SWZ16(r, lk));
    }
#pragma unroll
    for (int ni = 0; ni < 6; ++ni) {
      int r = ni * 16 + lrow;
      b_h[ni] = *(const bf16x8*)((const char*)Wh_s + SWZ16(r, lk));
      b_l[ni] = *(const bf16x8*)((const char*)Wl_s + SWZ16(r, lk));
    }
#pragma unroll
    for (int mi = 0; mi < 2; ++mi)
#pragma unroll
      for (int ni = 0; ni < 6; ++ni) {
        acc[mi][ni] = __builtin_amdgcn_mfma_f32_16x16x32_bf16(a_h[mi], b_h[ni], acc[mi][ni], 0, 0, 0);
        acc[mi][ni] = __builtin_amdgcn_mfma_f32_16x16x32_bf16(a_h[mi], b_l[ni], acc[mi][ni], 0, 0, 0);
        acc[mi][ni] = __builtin_amdgcn_mfma_f32_16x16x32_bf16(a_l[mi], b_h[ni], acc[mi][ni], 0, 0, 0);
      }
  }

#pragma unroll
  for (int mi = 0; mi < 2; ++mi) {
#pragma unroll
    for (int ni = 0; ni < 6; ++ni) {
      int mrow = m0 + wv * 32 + mi * 16 + (lane >> 4) * 4;
      int ncol = ni * 16 + (lane & 15);
#pragma unroll
      for (int rg = 0; rg < 4; ++rg) {
        Pt[((size_t)kc * BT_ + mrow + rg) * NX_ + ncol] = acc[mi][ni][rg];
      }
    }
  }
}

// ---------------- K4 (fused): reduce Pt chunks -> xdbl (LDS + global) -> delta
__global__ __launch_bounds__(256) void xdbl_delta_kernel(const float* __restrict__ Pt,
                                                         float* __restrict__ xdbl,
                                                         const float* __restrict__ Wdt,
                                                         const float* __restrict__ dtb,
                                                         float* __restrict__ delta) {
  __shared__ float xs[8][NX_];
  const int m0 = blockIdx.x * 8;
  const int tid = threadIdx.x;
  // reduce the 8 K-chunk partials for 8 rows x 96 cols
  for (int i = tid; i < 8 * NX_; i += 256) {
    int mi = i / NX_, ccol = i - mi * NX_;
    size_t off = (size_t)(m0 + mi) * NX_ + ccol;
    float s = 0.f;
#pragma unroll
    for (int kc = 0; kc < KC_; ++kc) s += Pt[(size_t)kc * BT_ * NX_ + off];
    xs[mi][ccol] = s;
    xdbl[off] = s;
  }
  __syncthreads();

  float acc[8][8];
#pragma unroll
  for (int mi = 0; mi < 8; ++mi)
#pragma unroll
    for (int j = 0; j < 8; ++j) acc[mi][j] = 0.f;

  for (int r = 0; r < R_; ++r) {
    float wd[8];
#pragma unroll
    for (int j = 0; j < 8; ++j) wd[j] = Wdt[(size_t)r * DI_ + tid + j * 256];
#pragma unroll
    for (int mi = 0; mi < 8; ++mi) {
      float xr = xs[mi][r];
#pragma unroll
      for (int j = 0; j < 8; ++j) acc[mi][j] += xr * wd[j];
    }
  }
#pragma unroll
  for (int j = 0; j < 8; ++j) {
    int d = tid + j * 256;
    float bias = dtb[d];
#pragma unroll
    for (int mi = 0; mi < 8; ++mi) {
      delta[(size_t)(m0 + mi) * DI_ + d] = softplus_f(acc[mi][j] + bias);
    }
  }
}

// ---------------- K5a: chunk scan, 4 lanes/channel x 4 states/lane -> (P, Q)
__global__ __launch_bounds__(256) void scanA_kernel(const float* __restrict__ delta,
                                                    const float* __restrict__ u,
                                                    const float* __restrict__ xdbl,
                                                    const float* __restrict__ A_logs,
                                                    float* __restrict__ P,
                                                    float* __restrict__ Q) {
  const int tid = threadIdx.x;
  const int q = tid & 3;                    // n-quad
  const int chan = blockIdx.x * 64 + (tid >> 2);
  const int c = blockIdx.y;
  const int b = chan >> 11;
  const int d = chan & (DI_ - 1);
  float Ac[4];
#pragma unroll
  for (int j = 0; j < 4; ++j) Ac[j] = -expf(A_logs[d * N_ + q * 4 + j]);
  const size_t base = (size_t)b * L_ * DI_ + d;
  const float* xd = xdbl + (size_t)b * L_ * NX_;
  float h[4] = {0.f, 0.f, 0.f, 0.f};
  float sdt = 0.f;
  const int t0 = c * LC_;
  for (int tt = 0; tt < LC_; ++tt) {
    int t = t0 + tt;
    float dt = delta[base + (size_t)t * DI_];
    float ut = u[base + (size_t)t * DI_];
    float4 Bt = *(const float4*)&xd[t * NX_ + R_ + q * 4];
    float du = dt * ut;
    float e0 = __expf(dt * Ac[0]), e1 = __expf(dt * Ac[1]);
    float e2 = __expf(dt * Ac[2]), e3 = __expf(dt * Ac[3]);
    h[0] = e0 * h[0] + du * Bt.x;
    h[1] = e1 * h[1] + du * Bt.y;
    h[2] = e2 * h[2] + du * Bt.z;
    h[3] = e3 * h[3] + du * Bt.w;
    sdt += dt;
  }
  size_t idx = ((size_t)chan * CH_ + c) * N_ + q * 4;
  *(float4*)&P[idx] = make_float4(__expf(Ac[0] * sdt), __expf(Ac[1] * sdt),
                                  __expf(Ac[2] * sdt), __expf(Ac[3] * sdt));
  *(float4*)&Q[idx] = make_float4(h[0], h[1], h[2], h[3]);
}

// ---------------- K5b: sequential combine over chunks -> H0
__global__ __launch_bounds__(256) void scanB_kernel(const float* __restrict__ P,
                                                    const float* __restrict__ Q,
                                                    float* __restrict__ H0) {
  int gid = blockIdx.x * 256 + threadIdx.x;  // over B*DI*N = 131072
  int chan = gid >> 4;
  int n = gid & 15;
  float h = 0.f;
  for (int c = 0; c < CH_; ++c) {
    size_t idx = ((size_t)chan * CH_ + c) * N_ + n;
    H0[idx] = h;
    h = P[idx] * h + Q[idx];
  }
}

// ---------------- K5c: replay with true initial state; y in-place over u
__global__ __launch_bounds__(256) void scanC_kernel(const float* __restrict__ delta,
                                                    float* uy,  // u in, y out (aliased)
                                                    const float* __restrict__ xdbl,
                                                    const float* __restrict__ A_logs,
                                                    const float* __restrict__ Ds,
                                                    const float* __restrict__ H0) {
  const int tid = threadIdx.x;
  const int q = tid & 3;
  const int chan = blockIdx.x * 64 + (tid >> 2);
  const int c = blockIdx.y;
  const int b = chan >> 11;
  const int d = chan & (DI_ - 1);
  float Ac[4];
#pragma unroll
  for (int j = 0; j < 4; ++j) Ac[j] = -expf(A_logs[d * N_ + q * 4 + j]);
  const float Dd = Ds[d];
  const size_t base = (size_t)b * L_ * DI_ + d;
  const float* dl = delta + base;
  float* ul = uy + base;
  const float* xd = xdbl + (size_t)b * L_ * NX_;
  float h[4];
  {
    float4 h0 = *(const float4*)&H0[((size_t)chan * CH_ + c) * N_ + q * 4];
    h[0] = h0.x; h[1] = h0.y; h[2] = h0.z; h[3] = h0.w;
  }
  const int t0 = c * LC_;
  for (int tt = 0; tt < LC_; ++tt) {
    int t = t0 + tt;
    float dt = dl[(size_t)t * DI_];
    float ut = ul[(size_t)t * DI_];
    float4 Bt = *(const float4*)&xd[t * NX_ + R_ + q * 4];
    float4 Ct = *(const float4*)&xd[t * NX_ + R_ + N_ + q * 4];
    float du = dt * ut;
    float e0 = __expf(dt * Ac[0]), e1 = __expf(dt * Ac[1]);
    float e2 = __expf(dt * Ac[2]), e3 = __expf(dt * Ac[3]);
    h[0] = e0 * h[0] + du * Bt.x;
    h[1] = e1 * h[1] + du * Bt.y;
    h[2] = e2 * h[2] + du * Bt.z;
    h[3] = e3 * h[3] + du * Bt.w;
    float p = h[0] * Ct.x + h[1] * Ct.y + h[2] * Ct.z + h[3] * Ct.w;
    p += __shfl_xor(p, 1);
    p += __shfl_xor(p, 2);
    if (q == 0) ul[(size_t)t * DI_] = p + Dd * ut;
  }
}

// ---------------- K6: per-row mean / rstd over DI
__global__ __launch_bounds__(256) void stats_kernel(const float* __restrict__ y,
                                                    float* __restrict__ mu,
                                                    float* __restrict__ rs) {
  __shared__ float red[4];
  const int row = blockIdx.x;
  const float* yr = y + (size_t)row * DI_;
  const int tid = threadIdx.x;
  float v[8];
  float s = 0.f;
#pragma unroll
  for (int j = 0; j < 8; ++j) { v[j] = yr[tid + j * 256]; s += v[j]; }
#pragma unroll
  for (int o = 1; o < 64; o <<= 1) s += __shfl_xor(s, o);
  if ((tid & 63) == 0) red[tid >> 6] = s;
  __syncthreads();
  float mu_v = (red[0] + red[1] + red[2] + red[3]) * (1.f / DI_);
  float q = 0.f;
#pragma unroll
  for (int j = 0; j < 8; ++j) { float dd = v[j] - mu_v; q += dd * dd; }
#pragma unroll
  for (int o = 1; o < 64; o <<= 1) q += __shfl_xor(q, o);
  __syncthreads();
  if ((tid & 63) == 0) red[tid >> 6] = q;
  __syncthreads();
  if (tid == 0) {
    float var = (red[0] + red[1] + red[2] + red[3]) * (1.f / DI_);
    mu[row] = mu_v;
    rs[row] = rsqrtf(var + 1e-5f);
  }
}

// ---------------- K7: v[b,d] = mean_t( ln(y)*z ), float4 y + bf16x4 z
__global__ __launch_bounds__(256) void vacc_kernel(const float* __restrict__ y,
                                                   const u16* __restrict__ zb,
                                                   const float* __restrict__ mu,
                                                   const float* __restrict__ rs,
                                                   const float* __restrict__ g,
                                                   const float* __restrict__ bb,
                                                   float* __restrict__ v) {
  const int d = (blockIdx.x * 256 + threadIdx.x) * 4;  // grid.x = DI/1024
  const int t0 = blockIdx.y * 16;                      // grid.y = L/16
  const int b = blockIdx.z;
  float4 gg = *(const float4*)&g[d];
  float4 bv = *(const float4*)&bb[d];
  float4 acc = make_float4(0.f, 0.f, 0.f, 0.f);
  for (int tt = 0; tt < 16; ++tt) {
    int row = b * L_ + t0 + tt;
    float4 yv = *(const float4*)&y[(size_t)row * DI_ + d];
    ushort4 zv = *(const ushort4*)&zb[(size_t)row * DI_ + d];
    float m = mu[row], r = rs[row];
    acc.x += ((yv.x - m) * r * gg.x + bv.x) * bf16_to_f(zv.x);
    acc.y += ((yv.y - m) * r * gg.y + bv.y) * bf16_to_f(zv.y);
    acc.z += ((yv.z - m) * r * gg.z + bv.z) * bf16_to_f(zv.z);
    acc.w += ((yv.w - m) * r * gg.w + bv.w) * bf16_to_f(zv.w);
  }
  atomicAdd(&v[b * DI_ + d + 0], acc.x * (1.f / L_));
  atomicAdd(&v[b * DI_ + d + 1], acc.y * (1.f / L_));
  atomicAdd(&v[b * DI_ + d + 2], acc.z * (1.f / L_));
  atomicAdd(&v[b * DI_ + d + 3], acc.w * (1.f / L_));
}

// ---------------- K8: out init = b_out
__global__ __launch_bounds__(256) void outinit_kernel(const float* __restrict__ b_out,
                                                      float* __restrict__ out) {
  int i = blockIdx.x * 256 + threadIdx.x;  // 0..4095
  out[i] = b_out[i & (DM_ - 1)];
}

// ---------------- K9: out += v @ W_out (partial over d-chunks, atomic)
__global__ __launch_bounds__(256) void outgemm_kernel(const float* __restrict__ v,
                                                      const float* __restrict__ Wout,
                                                      float* __restrict__ out) {
  const int m = blockIdx.x * 256 + threadIdx.x;  // 0..1023
  const int d0 = blockIdx.y * 128;
  float a0 = 0.f, a1 = 0.f, a2 = 0.f, a3 = 0.f;
  for (int dd = 0; dd < 128; ++dd) {
    float w = Wout[(size_t)(d0 + dd) * DM_ + m];
    a0 += v[0 * DI_ + d0 + dd] * w;
    a1 += v[1 * DI_ + d0 + dd] * w;
    a2 += v[2 * DI_ + d0 + dd] * w;
    a3 += v[3 * DI_ + d0 + dd] * w;
  }
  atomicAdd(&out[0 * DM_ + m], a0);
  atomicAdd(&out[1 * DM_ + m], a1);
  atomicAdd(&out[2 * DM_ + m], a2);
  atomicAdd(&out[3 * DM_ + m], a3);
}

extern "C" void kernel_launch(void* const* d_in, const int* in_sizes, int n_in,
                              void* d_out, int out_size, void* d_ws, size_t ws_size,
                              hipStream_t stream) {
  const float* x      = (const float*)d_in[0];
  const float* W_in   = (const float*)d_in[1];
  const float* conv_w = (const float*)d_in[2];
  const float* conv_b = (const float*)d_in[3];
  const float* W_x    = (const float*)d_in[4];
  const float* W_dt   = (const float*)d_in[5];
  const float* dt_bias= (const float*)d_in[6];
  const float* A_logs = (const float*)d_in[7];
  const float* Ds     = (const float*)d_in[8];
  const float* ln_g   = (const float*)d_in[9];
  const float* ln_b   = (const float*)d_in[10];
  const float* W_out  = (const float*)d_in[11];
  const float* b_out  = (const float*)d_in[12];
  float* out = (float*)d_out;

  float* ws = (float*)d_ws;
  const size_t BIG = (size_t)BT_ * DI_;          // 8,388,608 floats
  float* xi_buf   = ws;                          // xi; later delta
  float* z_buf    = ws + BIG;                    // silu(z) as bf16
  float* u_buf    = ws + 2 * BIG;                // xh/xl pre-split, then u, later y (in-place)
  float* xdbl_buf = ws + 3 * BIG;                // 4096*96
  float* mu_buf   = xdbl_buf + (size_t)BT_ * NX_;
  float* rs_buf   = mu_buf + BT_;
  float* v_buf    = rs_buf + BT_;                // B*DI
  float* P_buf    = v_buf + (size_t)B_ * DI_;    // B*DI*CH*N = 2,097,152 floats
  float* Q_buf    = P_buf + (size_t)B_ * DI_ * CH_ * N_;
  float* H0_buf   = Q_buf + (size_t)B_ * DI_ * CH_ * N_;

  u16* wt_hi = (u16*)P_buf;                      // W_in^T hi/lo (dead after gemm1)
  u16* wt_lo = (u16*)Q_buf;
  u16* wx_hi = (u16*)H0_buf;                     // Wx^T hi/lo (dead until scanB)
  u16* wx_lo = wx_hi + (size_t)NX_ * DI_;
  u16* xh = (u16*)u_buf;                         // x hi/lo (dead until conv writes u)
  u16* xl = xh + (size_t)BT_ * DM_;
  u16* zb = (u16*)z_buf;                         // z as bf16
  // Pt (8 x 4096 x 96 = 12.6 MB) spans P_buf+Q_buf (16.8 MB) — wt dead after
  // gemm1; P/Q written by scanA only after xdbl_delta consumes Pt.
  float* xdbl_part = P_buf;

  hipMemsetAsync(v_buf, 0, (size_t)B_ * DI_ * sizeof(float), stream);

  wsplit_kernel<<<dim3((2 * DI_) / 32, DM_ / 32), 256, 0, stream>>>(W_in, wt_hi, wt_lo);
  xsplit_kernel<<<(BT_ * DM_) / 1024, 256, 0, stream>>>(x, xh, xl);
  gemm1_mfma<<<dim3(BT_ / 128, (2 * DI_) / 256), 512, 0, stream>>>(xh, xl, wt_hi, wt_lo,
                                                                   xi_buf, zb);
  conv_silu_kernel<<<(BT_ * DI_) / 1024, 256, 0, stream>>>(xi_buf, conv_w, conv_b, u_buf);
  wxsplit_kernel<<<(NX_ * DI_) / 256, 256, 0, stream>>>(W_x, wx_hi, wx_lo);
  xdbl_mfma<<<dim3(BT_ / 128, KC_), 256, 0, stream>>>(u_buf, wx_hi, wx_lo, xdbl_part);
  xdbl_delta_kernel<<<BT_ / 8, 256, 0, stream>>>(xdbl_part, xdbl_buf, W_dt, dt_bias, xi_buf);
  scanA_kernel<<<dim3((B_ * DI_) / 64, CH_), 256, 0, stream>>>(xi_buf, u_buf, xdbl_buf,
                                                               A_logs, P_buf, Q_buf);
  scanB_kernel<<<(B_ * DI_ * N_) / 256, 256, 0, stream>>>(P_buf, Q_buf, H0_buf);
  scanC_kernel<<<dim3((B_ * DI_) / 64, CH_), 256, 0, stream>>>(xi_buf, u_buf, xdbl_buf,
                                                               A_logs, Ds, H0_buf);
  stats_kernel<<<BT_, 256, 0, stream>>>(u_buf, mu_buf, rs_buf);
  vacc_kernel<<<dim3(DI_ / 1024, L_ / 16, B_), 256, 0, stream>>>(u_buf, zb, mu_buf, rs_buf,
                                                                 ln_g, ln_b, v_buf);
  outinit_kernel<<<(B_ * DM_) / 256, 256, 0, stream>>>(b_out, out);
  outgemm_kernel<<<dim3(DM_ / 256, DI_ / 128), 256, 0, stream>>>(v_buf, W_out, out);
}